// Round 14
// baseline (62.196 us; speedup 1.0000x reference)
//
#include <hip/hip_runtime.h>
#include <hip/hip_bf16.h>

#define BB 1024
#define DD 256
#define NREL 42
#define ASCALE 128.0f
#define AINV (1.0f / 128.0f)

typedef __attribute__((ext_vector_type(8))) short short8_t;
typedef __attribute__((ext_vector_type(4))) short short4_t;
typedef __attribute__((ext_vector_type(4))) float f32x4;
typedef __attribute__((ext_vector_type(4))) int   i32x4;
typedef __attribute__((ext_vector_type(2))) unsigned int u32x2;

__device__ __forceinline__ unsigned short bf16_of(float f) {
    unsigned u = __float_as_uint(f);
    return (unsigned short)((u + 0x7FFFu + ((u >> 16) & 1u)) >> 16);
}

__device__ __forceinline__ long pack_fp8x8(const float* v) {
    // 8 floats -> 8 e4m3 bytes (low-to-high), RNE+sat via v_cvt_pk_fp8_f32
    int lo = __builtin_amdgcn_cvt_pk_fp8_f32(v[0], v[1], 0, false);
    lo     = __builtin_amdgcn_cvt_pk_fp8_f32(v[2], v[3], lo, true);
    int hi = __builtin_amdgcn_cvt_pk_fp8_f32(v[4], v[5], 0, false);
    hi     = __builtin_amdgcn_cvt_pk_fp8_f32(v[6], v[7], hi, true);
    return ((long)(unsigned)hi << 32) | (unsigned)lo;
}

// ---------------- K0: x -> fp8 fragment-major xq + bf16 transposed xbfT ---------
// xq layout: for 16-row j-group jg, K-step ks, lane l holds fp8 x[jg*16+(l&15)]
// [ks*32+(l>>4)*8 .. +8]. Byte addr ((jg*8+ks)*64 + l)*8 -> a wave's B-fragment
// load is ONE coalesced 512 B global_load_dwordx2.
__global__ __launch_bounds__(256) void cvt_kernel(const float* __restrict__ x,
                                                  unsigned char* __restrict__ xq,
                                                  unsigned short* __restrict__ xbfT) {
    __shared__ unsigned short t[64][72];
    const int bj = blockIdx.x * 64;
    const int bd = blockIdx.y * 64;
    const int tid = threadIdx.x;
    const int tr = tid >> 4;
    const int tc = tid & 15;

    #pragma unroll
    for (int rr = 0; rr < 4; ++rr) {
        const int jl = rr * 16 + tr;
        const f32x4 v = *reinterpret_cast<const f32x4*>(&x[(bj + jl) * DD + bd + tc * 4]);
        short4_t h;
        #pragma unroll
        for (int e = 0; e < 4; ++e) h[e] = (short)bf16_of(v[e]);
        *reinterpret_cast<short4_t*>(&t[jl][tc * 4]) = h;
    }
    __syncthreads();

    // fp8 fragment-major: 64 rows x 8 d8-chunks = 512 chunks over 256 threads
    #pragma unroll
    for (int c = 0; c < 2; ++c) {
        const int idx = c * 256 + tid;
        const int jl  = idx & 63;
        const int d8  = (idx >> 6) * 8;
        const int j   = bj + jl, d = bd + d8;
        const int jg = j >> 4, lc = j & 15, ks = d >> 5, g2 = (d >> 3) & 3;
        float f[8];
        #pragma unroll
        for (int e = 0; e < 8; ++e)
            f[e] = __uint_as_float((unsigned)t[jl][d8 + e] << 16);
        const long pk = pack_fp8x8(f);
        *reinterpret_cast<long*>(
            &xq[(size_t)(((jg * 8 + ks) * 64) + g2 * 16 + lc) * 8]) = pk;
    }

    // bf16 transposed copy for the output GEMM (PV keeps bf16 precision)
    #pragma unroll
    for (int rr = 0; rr < 4; ++rr) {
        const int dl = rr * 16 + tr;
        short4_t h;
        #pragma unroll
        for (int e = 0; e < 4; ++e) h[e] = (short)t[tc * 4 + e][dl];
        *reinterpret_cast<short4_t*>(&xbfT[(bd + dl) * BB + bj + tc * 4]) = h;
    }
}

// ---------------- K1 (fused): fp8 logits GEMM + gather + softmax -> P -----------
// 512 blocks x 256 thr (4 waves; 2 blocks/CU -> 8 waves/CU). Block = rows
// {i0, i0+1}; EVERY wave serves BOTH rows (A for 2 i's in fp8 registers, 6 MFMA
// per loaded B fragment) and owns j-quarter w (16 subtiles of 16 j).
// B fragments direct global->reg from fp8 fragment-major xq (512 B coalesced
// per load), ping-pong, NO LDS staging, NO K-loop barriers. Per subtile:
// 8 loads + 48 MFMA. A scaled x128 into e4m3 range; gathered logit rescaled.
__global__ __launch_bounds__(256) void attn_kernel(const float* __restrict__ x,
                                                   const int* __restrict__ q,
                                                   const float* __restrict__ R,
                                                   const unsigned char* __restrict__ xq,
                                                   unsigned short* __restrict__ P) {
    __shared__ float s_attn[2][BB];           // per-i logit row (8 KB)
    __shared__ unsigned short s_qs[2][BB];    // per-i q row (4 KB)

    const int tid  = threadIdx.x;
    const int w    = tid >> 6;       // 0..3: j-quarter
    const int lane = tid & 63;
    const int lcol = lane & 15;
    const int g    = lane >> 4;
    const int lk8  = g * 8;
    const int i0   = blockIdx.x * 2;

    // --- q rows -> LDS (u16): 2 rows x 1024 over 256 threads, 8 each ---
    {
        const int r  = tid >> 7;
        const int c8 = (tid & 127) * 8;
        const int qi = i0 + r;
        const i32x4 qa = *reinterpret_cast<const i32x4*>(&q[qi * BB + c8]);
        const i32x4 qb = *reinterpret_cast<const i32x4*>(&q[qi * BB + c8 + 4]);
        short4_t sa, sb;
        sa[0] = (short)qa[0]; sa[1] = (short)qa[1]; sa[2] = (short)qa[2]; sa[3] = (short)qa[3];
        sb[0] = (short)qb[0]; sb[1] = (short)qb[1]; sb[2] = (short)qb[2]; sb[3] = (short)qb[3];
        *reinterpret_cast<short4_t*>(&s_qs[r][c8])     = sa;
        *reinterpret_cast<short4_t*>(&s_qs[r][c8 + 4]) = sb;
    }

    // --- A fragments (fp8, x128) for BOTH rows: afr[i2][mt*8+ks] ---
    long afr[2][24];
    #pragma unroll
    for (int i2 = 0; i2 < 2; ++i2) {
        const int i = i0 + i2;
        #pragma unroll
        for (int ks = 0; ks < 8; ++ks) {
            const int d0 = ks * 32 + lk8;
            const f32x4 x0 = *reinterpret_cast<const f32x4*>(&x[i * DD + d0]);
            const f32x4 x1 = *reinterpret_cast<const f32x4*>(&x[i * DD + d0 + 4]);
            #pragma unroll
            for (int mt = 0; mt < 3; ++mt) {
                const int k = mt * 16 + lcol;
                long frag = 0;
                if (k < NREL) {
                    const f32x4 r0 = *reinterpret_cast<const f32x4*>(&R[k * DD + d0]);
                    const f32x4 r1 = *reinterpret_cast<const f32x4*>(&R[k * DD + d0 + 4]);
                    float f[8];
                    #pragma unroll
                    for (int e = 0; e < 4; ++e) {
                        f[e]     = r0[e] * x0[e] * ASCALE;
                        f[e + 4] = r1[e] * x1[e] * ASCALE;
                    }
                    frag = pack_fp8x8(f);
                }
                afr[i2][mt * 8 + ks] = frag;
            }
        }
    }

    __syncthreads();   // s_qs ready

    // Wave's B-fragment stream: subtile s covers j-group jg = w*16 + s.
    const unsigned char* fbase = xq + (size_t)(w * 16) * 512 * 8 + lane * 8;

    long ba[8], bb[8];

    auto loadb = [&](long (&b)[8], int s_) {
        const int sc = (s_ < 16) ? s_ : 15;
        const unsigned char* base = fbase + (size_t)sc * 4096;
        #pragma unroll
        for (int k = 0; k < 8; ++k)
            b[k] = *reinterpret_cast<const long*>(base + k * 512);
    };
    auto computeb = [&](long (&b)[8], int s_) {
        f32x4 acc[2][3];
        #pragma unroll
        for (int i2 = 0; i2 < 2; ++i2)
            #pragma unroll
            for (int mt = 0; mt < 3; ++mt)
                acc[i2][mt] = (f32x4)0.0f;

        #pragma unroll
        for (int ks = 0; ks < 8; ++ks)
            #pragma unroll
            for (int i2 = 0; i2 < 2; ++i2)
                #pragma unroll
                for (int mt = 0; mt < 3; ++mt)
                    acc[i2][mt] = __builtin_amdgcn_mfma_f32_16x16x32_fp8_fp8(
                        afr[i2][mt * 8 + ks], b[ks], acc[i2][mt], 0, 0, 0);

        // Gather: exactly one lane per j holds S[q[i,j], j] (col=lcol, row=g*4+r)
        const int jl = (w * 16 + s_) * 16 + lcol;
        #pragma unroll
        for (int i2 = 0; i2 < 2; ++i2) {
            const int qv = (int)s_qs[i2][jl];
            if (((qv >> 2) & 3) == g) {
                const int mt = qv >> 4;                       // 0..2 (qv < 42)
                const f32x4 av = (mt == 0) ? acc[i2][0] : (mt == 1) ? acc[i2][1] : acc[i2][2];
                const float v = (qv & 2) ? ((qv & 1) ? av[3] : av[2])
                                         : ((qv & 1) ? av[1] : av[0]);
                s_attn[i2][jl] = v * AINV;
            }
        }
    };

    loadb(ba, 0);
    for (int s = 0; s < 16; s += 2) {
        loadb(bb, s + 1);   // prefetch next subtile
        computeb(ba, s);
        loadb(ba, s + 2);   // prefetch next-next
        computeb(bb, s + 1);
    }

    __syncthreads();   // s_attn complete

    // --- softmax: wave w reduces row (w&1) fully, writes half (w>>1) of P ---
    const int p2 = w & 1;
    const int jh = w >> 1;
    const int i  = i0 + p2;

    f32x4 v4[4];
    #pragma unroll
    for (int kk = 0; kk < 4; ++kk)
        v4[kk] = *reinterpret_cast<const f32x4*>(&s_attn[p2][kk * 256 + lane * 4]);

    float m = -1e30f;
    #pragma unroll
    for (int kk = 0; kk < 4; ++kk)
        m = fmaxf(m, fmaxf(fmaxf(v4[kk][0], v4[kk][1]), fmaxf(v4[kk][2], v4[kk][3])));
    #pragma unroll
    for (int off = 1; off < 64; off <<= 1) m = fmaxf(m, __shfl_xor(m, off));

    float e[16];
    float ssum = 0.f;
    #pragma unroll
    for (int kk = 0; kk < 4; ++kk)
        #pragma unroll
        for (int ee = 0; ee < 4; ++ee) {
            const float t2 = __expf(v4[kk][ee] - m);
            e[kk * 4 + ee] = t2;
            ssum += t2;
        }
    #pragma unroll
    for (int off = 1; off < 64; off <<= 1) ssum += __shfl_xor(ssum, off);
    const float inv = 1.0f / ssum;

    #pragma unroll
    for (int kk2 = 0; kk2 < 2; ++kk2) {
        const int kk = jh * 2 + kk2;
        short4_t pv;
        #pragma unroll
        for (int ee = 0; ee < 4; ++ee) pv[ee] = (short)bf16_of(e[kk * 4 + ee] * inv);
        *reinterpret_cast<short4_t*>(&P[i * BB + kk * 256 + lane * 4]) = pv;
    }
}

// ---------------- K3a: partial out GEMM, split-K z=4 (bf16) ---------------------
__global__ __launch_bounds__(256) void out_partial(const unsigned short* __restrict__ P,
                                                   const unsigned short* __restrict__ xbfT,
                                                   float* __restrict__ part) {
    const int tid = threadIdx.x;
    const int wave = tid >> 6, lane = tid & 63;
    const int lcol = lane & 15;
    const int lk8  = (lane >> 4) * 8;
    const int i0 = blockIdx.y * 64 + wave * 16;
    const int d0 = blockIdx.x * 64;
    const int k0 = blockIdx.z * 256;

    f32x4 acc[4];
    #pragma unroll
    for (int nt = 0; nt < 4; ++nt) acc[nt] = (f32x4)0.0f;

    #pragma unroll
    for (int ks = 0; ks < 8; ++ks) {
        const short8_t a = *reinterpret_cast<const short8_t*>(
            &P[(i0 + lcol) * BB + k0 + ks * 32 + lk8]);
        #pragma unroll
        for (int nt = 0; nt < 4; ++nt) {
            const short8_t b = *reinterpret_cast<const short8_t*>(
                &xbfT[(d0 + nt * 16 + lcol) * BB + k0 + ks * 32 + lk8]);
            acc[nt] = __builtin_amdgcn_mfma_f32_16x16x32_bf16(a, b, acc[nt], 0, 0, 0);
        }
    }

    const int rbase = (lane >> 4) * 4;
    float* pz = part + (size_t)blockIdx.z * BB * DD;
    #pragma unroll
    for (int r = 0; r < 4; ++r)
        #pragma unroll
        for (int nt = 0; nt < 4; ++nt)
            pz[(i0 + rbase + r) * DD + d0 + nt * 16 + lcol] = acc[nt][r];
}

// ---------------- K3b: out = sum_z part[z] (P already normalized) ---------------
__global__ __launch_bounds__(256) void out_reduce(const float* __restrict__ part,
                                                  float* __restrict__ out) {
    const int idx = blockIdx.x * DD + threadIdx.x;
    out[idx] = (part[idx] + part[BB * DD + idx]) +
               (part[2 * BB * DD + idx] + part[3 * BB * DD + idx]);
}

// ---------------- launch ---------------------------------------------------------
extern "C" void kernel_launch(void* const* d_in, const int* in_sizes, int n_in,
                              void* d_out, int out_size, void* d_ws, size_t ws_size,
                              hipStream_t stream) {
    (void)in_sizes; (void)n_in; (void)out_size; (void)ws_size;
    const float* x = (const float*)d_in[0];
    // d_in[1] = x_mask (unused), d_in[3] = f (unused)
    const int* q = (const int*)d_in[2];
    const float* R = (const float*)d_in[4];
    float* out = (float*)d_out;

    char* ws = (char*)d_ws;
    unsigned char*  xq   = (unsigned char*)(ws);                   // 256 KB
    unsigned short* xbfT = (unsigned short*)(ws + (256u << 10));   // 512 KB
    unsigned short* P    = (unsigned short*)(ws + (768u << 10));   // 2 MB
    float*          part = (float*)(ws + (2816u << 10));           // 4 MB (z=4)

    cvt_kernel<<<dim3(16, 4), 256, 0, stream>>>(x, xq, xbfT);
    attn_kernel<<<dim3(512), 256, 0, stream>>>(x, q, R, xq, P);
    out_partial<<<dim3(4, 16, 4), 256, 0, stream>>>(P, xbfT, part);
    out_reduce<<<dim3(BB), 256, 0, stream>>>(part, out);
}

// Round 15
// 52.507 us; speedup vs baseline: 1.1845x; 1.1845x over previous
//
#include <hip/hip_runtime.h>
#include <hip/hip_bf16.h>

#define BB 1024
#define DD 256
#define NREL 42

typedef __attribute__((ext_vector_type(8))) short short8_t;
typedef __attribute__((ext_vector_type(4))) short short4_t;
typedef __attribute__((ext_vector_type(4))) float f32x4;
typedef __attribute__((ext_vector_type(4))) int   i32x4;

__device__ __forceinline__ unsigned short bf16_of(float f) {
    // round-to-nearest-even f32 -> bf16 (inputs are finite normals)
    unsigned u = __float_as_uint(f);
    return (unsigned short)((u + 0x7FFFu + ((u >> 16) & 1u)) >> 16);
}

// ---------------- K0: x -> bf16: fragment-major xfrag + transposed xbfT ----------
// xfrag layout: for 16-row j-group jg and K-step ks, lane l (l=0..63) holds
// bf16 x[jg*16 + (l&15)][ks*32 + (l>>4)*8 .. +8]  (the exact MFMA B fragment).
// Flat index: ((jg*8 + ks)*64 + l)*8 shorts -> a wave's B-fragment load is ONE
// fully-coalesced 1 KB global_load_dwordx4.
__global__ __launch_bounds__(256) void cvt_kernel(const float* __restrict__ x,
                                                  unsigned short* __restrict__ xfrag,
                                                  unsigned short* __restrict__ xbfT) {
    __shared__ unsigned short t[64][72];
    const int bj = blockIdx.x * 64;
    const int bd = blockIdx.y * 64;
    const int tid = threadIdx.x;
    const int tr = tid >> 4;
    const int tc = tid & 15;

    #pragma unroll
    for (int rr = 0; rr < 4; ++rr) {
        const int jl = rr * 16 + tr;
        const f32x4 v = *reinterpret_cast<const f32x4*>(&x[(bj + jl) * DD + bd + tc * 4]);
        short4_t h;
        #pragma unroll
        for (int e = 0; e < 4; ++e) h[e] = (short)bf16_of(v[e]);
        *reinterpret_cast<short4_t*>(&t[jl][tc * 4]) = h;
    }
    __syncthreads();

    // fragment-major writes: 64 rows x 8 d8-chunks = 512 chunks over 256 threads
    #pragma unroll
    for (int c = 0; c < 2; ++c) {
        const int idx = c * 256 + tid;
        const int jl  = idx & 63;
        const int d8  = (idx >> 6) * 8;
        const int j   = bj + jl, d = bd + d8;
        const int jg = j >> 4, lc = j & 15, ks = d >> 5, g2 = (d >> 3) & 3;
        const short8_t v = *reinterpret_cast<const short8_t*>(&t[jl][d8]);
        *reinterpret_cast<short8_t*>(
            &xfrag[(size_t)(((jg * 8 + ks) * 64) + g2 * 16 + lc) * 8]) = v;
    }

    // transposed copy for the output GEMM
    #pragma unroll
    for (int rr = 0; rr < 4; ++rr) {
        const int dl = rr * 16 + tr;
        short4_t h;
        #pragma unroll
        for (int e = 0; e < 4; ++e) h[e] = (short)t[tc * 4 + e][dl];
        *reinterpret_cast<short4_t*>(&xbfT[(bd + dl) * BB + bj + tc * 4]) = h;
    }
}

// ---------------- K1 (fused): logits GEMM + gather + softmax -> normalized P ----
// EMPIRICAL OPTIMUM (round 9, 43 us attn / 52.5 us total). All probed
// neighbors regress: 4 waves/SIMD (r12 62us), 4-buffer depth (r13 55-59us),
// fp8+2rows/wave (r14 78us), LDS staging / barrier variants (r4-r8 57-86us).
// 512 blocks x 256 thr (4 waves; 2 blocks/CU -> 2 waves/SIMD, independent).
// Wave w: p=w&1 -> row i=blk*2+p; jh=w>>1 -> j-half (32 subtiles of 16 j).
// Wave pairs (same jh, diff p) share the identical B-load stream -> L1 hits.
// A_i (48x256 bf16) in VGPRs. B fragments loaded DIRECTLY global->reg from
// fragment-major xfrag (1 KB coalesced per load, L2-resident), ping-pong
// buffered, NO LDS staging, NO barriers in the K-loop. Per 16-j subtile:
// 8 loads + 24 MFMA (3 acc chains). Epilogue gathers S[q[i,j], j]; pre-softmax
// barrier; per-wave full-row softmax writes its P half.
__global__ __launch_bounds__(256) void attn_kernel(const float* __restrict__ x,
                                                   const int* __restrict__ q,
                                                   const float* __restrict__ R,
                                                   const unsigned short* __restrict__ xfrag,
                                                   unsigned short* __restrict__ P) {
    __shared__ float s_attn[2][BB];           // per-i logit row (8 KB)
    __shared__ unsigned short s_qs[2][BB];    // per-i q row (4 KB)

    const int tid  = threadIdx.x;
    const int w    = tid >> 6;       // 0..3
    const int lane = tid & 63;
    const int p    = w & 1;          // which i this wave serves
    const int jh   = w >> 1;         // which 512-j half
    const int lcol = lane & 15;
    const int g    = lane >> 4;
    const int lk8  = g * 8;
    const int i    = blockIdx.x * 2 + p;

    // --- q rows -> LDS (u16): 2 rows x 1024 over 256 threads, 8 each ---
    {
        const int r  = tid >> 7;
        const int c8 = (tid & 127) * 8;
        const int qi = blockIdx.x * 2 + r;
        const i32x4 qa = *reinterpret_cast<const i32x4*>(&q[qi * BB + c8]);
        const i32x4 qb = *reinterpret_cast<const i32x4*>(&q[qi * BB + c8 + 4]);
        short4_t sa, sb;
        sa[0] = (short)qa[0]; sa[1] = (short)qa[1]; sa[2] = (short)qa[2]; sa[3] = (short)qa[3];
        sb[0] = (short)qb[0]; sb[1] = (short)qb[1]; sb[2] = (short)qb[2]; sb[3] = (short)qb[3];
        *reinterpret_cast<short4_t*>(&s_qs[r][c8])     = sa;
        *reinterpret_cast<short4_t*>(&s_qs[r][c8 + 4]) = sb;
    }

    // --- A_i fragments in registers: afrag[mt*8+ks] = bf16(R[k][d]*x[i][d]) ---
    short8_t afrag[24];
    #pragma unroll
    for (int ks = 0; ks < 8; ++ks) {
        const int d0 = ks * 32 + lk8;
        const f32x4 x0 = *reinterpret_cast<const f32x4*>(&x[i * DD + d0]);
        const f32x4 x1 = *reinterpret_cast<const f32x4*>(&x[i * DD + d0 + 4]);
        #pragma unroll
        for (int mt = 0; mt < 3; ++mt) {
            const int k = mt * 16 + lcol;
            short8_t v = (short8_t)0;
            if (k < NREL) {
                const f32x4 r0 = *reinterpret_cast<const f32x4*>(&R[k * DD + d0]);
                const f32x4 r1 = *reinterpret_cast<const f32x4*>(&R[k * DD + d0 + 4]);
                #pragma unroll
                for (int e = 0; e < 4; ++e) {
                    v[e]     = (short)bf16_of(r0[e] * x0[e]);
                    v[e + 4] = (short)bf16_of(r1[e] * x1[e]);
                }
            }
            afrag[mt * 8 + ks] = v;
        }
    }

    __syncthreads();   // s_qs ready

    // Wave's B-fragment stream: subtile s covers j-group jg = jh*32 + s.
    const unsigned short* fbase = xfrag + (size_t)(jh * 32) * 4096 + lane * 8;

    short8_t ba[8], bb[8];

    auto loadb = [&](short8_t (&b)[8], int s_) {
        const unsigned short* base = fbase + (size_t)s_ * 4096;
        #pragma unroll
        for (int k = 0; k < 8; ++k)
            b[k] = *reinterpret_cast<const short8_t*>(base + k * 512);
    };
    auto computeb = [&](short8_t (&b)[8], int s_) {
        f32x4 a0 = (f32x4)0.0f, a1 = (f32x4)0.0f, a2 = (f32x4)0.0f;
        #pragma unroll
        for (int ks = 0; ks < 8; ++ks) {
            a0 = __builtin_amdgcn_mfma_f32_16x16x32_bf16(afrag[ks],      b[ks], a0, 0, 0, 0);
            a1 = __builtin_amdgcn_mfma_f32_16x16x32_bf16(afrag[8 + ks],  b[ks], a1, 0, 0, 0);
            a2 = __builtin_amdgcn_mfma_f32_16x16x32_bf16(afrag[16 + ks], b[ks], a2, 0, 0, 0);
        }
        // Exactly one lane per j holds S[q[i,j], j]: col=lcol, row=g*4+r.
        const int jl = (jh * 32 + s_) * 16 + lcol;
        const int qv = (int)s_qs[p][jl];
        if (((qv >> 2) & 3) == g) {
            const int mt = qv >> 4;                       // 0..2 (qv < 42)
            const f32x4 av = (mt == 0) ? a0 : (mt == 1) ? a1 : a2;
            const float v = (qv & 2) ? ((qv & 1) ? av[3] : av[2])
                                     : ((qv & 1) ? av[1] : av[0]);
            s_attn[p][jl] = v;
        }
    };

    loadb(ba, 0);
    for (int s = 0; s < 32; s += 2) {
        loadb(bb, (s + 1 < 32) ? s + 1 : 31);   // prefetch next subtile
        computeb(ba, s);
        loadb(ba, (s + 2 < 32) ? s + 2 : 31);   // prefetch next-next
        computeb(bb, s + 1);
    }

    __syncthreads();   // s_attn complete

    // --- softmax: full-row reduce (redundant in wave pair), write own P half ---
    f32x4 v4[4];
    #pragma unroll
    for (int kk = 0; kk < 4; ++kk)
        v4[kk] = *reinterpret_cast<const f32x4*>(&s_attn[p][kk * 256 + lane * 4]);

    float m = -1e30f;
    #pragma unroll
    for (int kk = 0; kk < 4; ++kk)
        m = fmaxf(m, fmaxf(fmaxf(v4[kk][0], v4[kk][1]), fmaxf(v4[kk][2], v4[kk][3])));
    #pragma unroll
    for (int off = 1; off < 64; off <<= 1) m = fmaxf(m, __shfl_xor(m, off));

    float e[16];
    float ssum = 0.f;
    #pragma unroll
    for (int kk = 0; kk < 4; ++kk)
        #pragma unroll
        for (int ee = 0; ee < 4; ++ee) {
            const float t2 = __expf(v4[kk][ee] - m);
            e[kk * 4 + ee] = t2;
            ssum += t2;
        }
    #pragma unroll
    for (int off = 1; off < 64; off <<= 1) ssum += __shfl_xor(ssum, off);
    const float inv = 1.0f / ssum;

    #pragma unroll
    for (int kk2 = 0; kk2 < 2; ++kk2) {
        const int kk = jh * 2 + kk2;
        short4_t pv;
        #pragma unroll
        for (int ee = 0; ee < 4; ++ee) pv[ee] = (short)bf16_of(e[kk * 4 + ee] * inv);
        *reinterpret_cast<short4_t*>(&P[i * BB + kk * 256 + lane * 4]) = pv;
    }
}

// ---------------- K3a: partial out GEMM, split-K z=4 -----------------------------
__global__ __launch_bounds__(256) void out_partial(const unsigned short* __restrict__ P,
                                                   const unsigned short* __restrict__ xbfT,
                                                   float* __restrict__ part) {
    const int tid = threadIdx.x;
    const int wave = tid >> 6, lane = tid & 63;
    const int lcol = lane & 15;
    const int lk8  = (lane >> 4) * 8;
    const int i0 = blockIdx.y * 64 + wave * 16;
    const int d0 = blockIdx.x * 64;
    const int k0 = blockIdx.z * 256;

    f32x4 acc[4];
    #pragma unroll
    for (int nt = 0; nt < 4; ++nt) acc[nt] = (f32x4)0.0f;

    #pragma unroll
    for (int ks = 0; ks < 8; ++ks) {
        const short8_t a = *reinterpret_cast<const short8_t*>(
            &P[(i0 + lcol) * BB + k0 + ks * 32 + lk8]);
        #pragma unroll
        for (int nt = 0; nt < 4; ++nt) {
            const short8_t b = *reinterpret_cast<const short8_t*>(
                &xbfT[(d0 + nt * 16 + lcol) * BB + k0 + ks * 32 + lk8]);
            acc[nt] = __builtin_amdgcn_mfma_f32_16x16x32_bf16(a, b, acc[nt], 0, 0, 0);
        }
    }

    const int rbase = (lane >> 4) * 4;
    float* pz = part + (size_t)blockIdx.z * BB * DD;
    #pragma unroll
    for (int r = 0; r < 4; ++r)
        #pragma unroll
        for (int nt = 0; nt < 4; ++nt)
            pz[(i0 + rbase + r) * DD + d0 + nt * 16 + lcol] = acc[nt][r];
}

// ---------------- K3b: out = sum_z part[z] (P already normalized) ---------------
__global__ __launch_bounds__(256) void out_reduce(const float* __restrict__ part,
                                                  float* __restrict__ out) {
    const int idx = blockIdx.x * DD + threadIdx.x;
    out[idx] = (part[idx] + part[BB * DD + idx]) +
               (part[2 * BB * DD + idx] + part[3 * BB * DD + idx]);
}

// ---------------- launch ---------------------------------------------------------
extern "C" void kernel_launch(void* const* d_in, const int* in_sizes, int n_in,
                              void* d_out, int out_size, void* d_ws, size_t ws_size,
                              hipStream_t stream) {
    (void)in_sizes; (void)n_in; (void)out_size; (void)ws_size;
    const float* x = (const float*)d_in[0];
    // d_in[1] = x_mask (unused), d_in[3] = f (unused)
    const int* q = (const int*)d_in[2];
    const float* R = (const float*)d_in[4];
    float* out = (float*)d_out;

    char* ws = (char*)d_ws;
    unsigned short* xfrag = (unsigned short*)(ws);                  // 512 KB
    unsigned short* xbfT  = (unsigned short*)(ws + (512u << 10));   // 512 KB
    unsigned short* P     = (unsigned short*)(ws + (1024u << 10));  // 2 MB
    float*          part  = (float*)(ws + (3072u << 10));           // 4 MB (z=4)

    cvt_kernel<<<dim3(16, 4), 256, 0, stream>>>(x, xfrag, xbfT);
    attn_kernel<<<dim3(512), 256, 0, stream>>>(x, q, R, xfrag, P);
    out_partial<<<dim3(4, 16, 4), 256, 0, stream>>>(P, xbfT, part);
    out_reduce<<<dim3(BB), 256, 0, stream>>>(part, out);
}

// Round 17
// 48.558 us; speedup vs baseline: 1.2809x; 1.0813x over previous
//
#include <hip/hip_runtime.h>
#include <hip/hip_bf16.h>

#define BB 1024
#define DD 256
#define NREL 42
#define AST 260   // bf16 halves/row: 520 B rows, 8B-aligned; 130 words %32=2 -> 16 bank residues

typedef __attribute__((ext_vector_type(8))) short short8_t;
typedef __attribute__((ext_vector_type(4))) short short4_t;
typedef __attribute__((ext_vector_type(4))) float f32x4;
typedef __attribute__((ext_vector_type(4))) int   i32x4;
typedef __attribute__((ext_vector_type(2))) unsigned int u32x2;
typedef __attribute__((ext_vector_type(4))) unsigned int u32x4;

__device__ __forceinline__ unsigned short bf16_of(float f) {
    // round-to-nearest-even f32 -> bf16 (inputs are finite normals)
    unsigned u = __float_as_uint(f);
    return (unsigned short)((u + 0x7FFFu + ((u >> 16) & 1u)) >> 16);
}

__device__ __forceinline__ float blo(unsigned u) { return __uint_as_float(u << 16); }
__device__ __forceinline__ float bhi(unsigned u) { return __uint_as_float(u & 0xFFFF0000u); }

// 8 bf16 terms: A halves in (al,ah), x halves in xv; f32 fma chain (exact expand)
__device__ __forceinline__ float dot8bf(u32x2 al, u32x2 ah, u32x4 xv, float acc) {
    acc = fmaf(blo(al[0]), blo(xv[0]), acc);
    acc = fmaf(bhi(al[0]), bhi(xv[0]), acc);
    acc = fmaf(blo(al[1]), blo(xv[1]), acc);
    acc = fmaf(bhi(al[1]), bhi(xv[1]), acc);
    acc = fmaf(blo(ah[0]), blo(xv[2]), acc);
    acc = fmaf(bhi(ah[0]), bhi(xv[2]), acc);
    acc = fmaf(blo(ah[1]), blo(xv[3]), acc);
    acc = fmaf(bhi(ah[1]), bhi(xv[3]), acc);
    return acc;
}

// ---------------- K0: x -> bf16 interleaved xh8 [d8][j][8] + bf16 transposed xbfT
__global__ __launch_bounds__(256) void cvt_kernel(const float* __restrict__ x,
                                                  unsigned short* __restrict__ xh8,
                                                  unsigned short* __restrict__ xbfT) {
    __shared__ float t32[64][68];
    const int bj = blockIdx.x * 64;
    const int bd = blockIdx.y * 64;
    const int tid = threadIdx.x;
    const int tr = tid >> 4;
    const int tc = tid & 15;

    #pragma unroll
    for (int rr = 0; rr < 4; ++rr) {
        const int jl = rr * 16 + tr;
        const f32x4 v = *reinterpret_cast<const f32x4*>(&x[(bj + jl) * DD + bd + tc * 4]);
        *reinterpret_cast<f32x4*>(&t32[jl][tc * 4]) = v;
    }
    __syncthreads();

    // bf16 transposed copy for the output GEMM
    #pragma unroll
    for (int rr = 0; rr < 4; ++rr) {
        const int dl = rr * 16 + tr;
        short4_t h;
        #pragma unroll
        for (int e = 0; e < 4; ++e) h[e] = (short)bf16_of(t32[tc * 4 + e][dl]);
        *reinterpret_cast<short4_t*>(&xbfT[(bd + dl) * BB + bj + tc * 4]) = h;
    }

    // bf16 interleaved: cell (jl, d8l); 512 cells over 256 threads
    #pragma unroll
    for (int c = 0; c < 2; ++c) {
        const int idx = c * 256 + tid;
        const int jl  = idx & 63;
        const int d8l = idx >> 6;           // 0..7
        short8_t hv;
        #pragma unroll
        for (int e = 0; e < 8; ++e) hv[e] = (short)bf16_of(t32[jl][d8l * 8 + e]);
        *reinterpret_cast<short8_t*>(
            &xh8[(size_t)((bd >> 3) + d8l) * (BB * 8) + (bj + jl) * 8]) = hv;
    }
}

// ---------------- K1 (fused): direct bf16 gather-dot + softmax -> normalized P --
// 1024 blocks x 256 thr (4 blocks/CU -> 16 waves/CU). Block = one i.
// A_i[k][d] = bf16(R[k][d]*x[i][d]) staged in LDS (42 x 260-stride halves).
// Each lane owns 4 j's: acc_j = sum_d A_i[q[i,j]][d] * x[j][d], computed by
// expanding bf16 -> f32 (u<<16 / u&0xFFFF0000) and f32 fmaf — EXACTLY the
// operand precision of the passing MFMA rounds (bf16 in, f32 acc). No fdot2,
// no f16 (round-16's failed novelties). x reads are 16B/lane fully-coalesced
// from the bf16-interleaved xh8; A reads are LDS b64 gathers (16 bank
// residues, ~4-way). NO MFMA: only the 268M needed FMAs, not 48x-redundant.
__global__ __launch_bounds__(256) void attn_kernel(const float* __restrict__ x,
                                                   const int* __restrict__ q,
                                                   const float* __restrict__ R,
                                                   const unsigned short* __restrict__ xh8,
                                                   unsigned short* __restrict__ P) {
    __shared__ unsigned short Ah[NREL * AST];   // 21840 B
    __shared__ float s_attn[BB];                // 4096 B
    __shared__ unsigned short s_qs[BB];         // 2048 B

    const int tid  = threadIdx.x;
    const int w    = tid >> 6;       // 0..3: j-quarter
    const int lane = tid & 63;
    const int i    = blockIdx.x;

    // --- q row -> LDS (u16) ---
    {
        const int c4 = tid * 4;
        const i32x4 qa = *reinterpret_cast<const i32x4*>(&q[i * BB + c4]);
        short4_t sa;
        sa[0] = (short)qa[0]; sa[1] = (short)qa[1];
        sa[2] = (short)qa[2]; sa[3] = (short)qa[3];
        *reinterpret_cast<short4_t*>(&s_qs[c4]) = sa;
    }

    // --- stage A_i (bf16): 42 rows x 32 chunks of 8 = 1344 chunks ---
    for (int c = tid; c < NREL * 32; c += 256) {
        const int k  = c >> 5;
        const int d0 = (c & 31) * 8;
        const f32x4 r0 = *reinterpret_cast<const f32x4*>(&R[k * DD + d0]);
        const f32x4 r1 = *reinterpret_cast<const f32x4*>(&R[k * DD + d0 + 4]);
        const f32x4 x0 = *reinterpret_cast<const f32x4*>(&x[i * DD + d0]);
        const f32x4 x1 = *reinterpret_cast<const f32x4*>(&x[i * DD + d0 + 4]);
        short4_t lo, hi;
        #pragma unroll
        for (int e = 0; e < 4; ++e) {
            lo[e] = (short)bf16_of(r0[e] * x0[e]);
            hi[e] = (short)bf16_of(r1[e] * x1[e]);
        }
        *reinterpret_cast<short4_t*>(&Ah[k * AST + d0])     = lo;   // 8B store
        *reinterpret_cast<short4_t*>(&Ah[k * AST + d0 + 4]) = hi;   // 8B store
    }

    __syncthreads();

    // --- 4 interleaved j-streams per lane ---
    const int j0 = w * 256 + lane;
    const unsigned short* a0 = &Ah[(int)s_qs[j0]       * AST];
    const unsigned short* a1 = &Ah[(int)s_qs[j0 + 64]  * AST];
    const unsigned short* a2 = &Ah[(int)s_qs[j0 + 128] * AST];
    const unsigned short* a3 = &Ah[(int)s_qs[j0 + 192] * AST];
    const unsigned short* xp = xh8 + (size_t)j0 * 8;

    float acc0 = 0.f, acc1 = 0.f, acc2 = 0.f, acc3 = 0.f;

    #pragma unroll 2
    for (int d8 = 0; d8 < 32; ++d8) {
        const unsigned short* xb = xp + (size_t)d8 * (BB * 8);
        const u32x4 xv0 = *reinterpret_cast<const u32x4*>(xb);
        const u32x4 xv1 = *reinterpret_cast<const u32x4*>(xb + 64 * 8);
        const u32x4 xv2 = *reinterpret_cast<const u32x4*>(xb + 128 * 8);
        const u32x4 xv3 = *reinterpret_cast<const u32x4*>(xb + 192 * 8);

        const int ao = d8 * 8;
        const u32x2 a0l = *reinterpret_cast<const u32x2*>(a0 + ao);
        const u32x2 a0h = *reinterpret_cast<const u32x2*>(a0 + ao + 4);
        const u32x2 a1l = *reinterpret_cast<const u32x2*>(a1 + ao);
        const u32x2 a1h = *reinterpret_cast<const u32x2*>(a1 + ao + 4);
        const u32x2 a2l = *reinterpret_cast<const u32x2*>(a2 + ao);
        const u32x2 a2h = *reinterpret_cast<const u32x2*>(a2 + ao + 4);
        const u32x2 a3l = *reinterpret_cast<const u32x2*>(a3 + ao);
        const u32x2 a3h = *reinterpret_cast<const u32x2*>(a3 + ao + 4);

        acc0 = dot8bf(a0l, a0h, xv0, acc0);
        acc1 = dot8bf(a1l, a1h, xv1, acc1);
        acc2 = dot8bf(a2l, a2h, xv2, acc2);
        acc3 = dot8bf(a3l, a3h, xv3, acc3);
    }

    s_attn[j0]       = acc0;
    s_attn[j0 + 64]  = acc1;
    s_attn[j0 + 128] = acc2;
    s_attn[j0 + 192] = acc3;

    __syncthreads();

    // --- softmax: full-row reduce (redundant x4), write own P quarter ---
    f32x4 v4[4];
    #pragma unroll
    for (int kk = 0; kk < 4; ++kk)
        v4[kk] = *reinterpret_cast<const f32x4*>(&s_attn[kk * 256 + lane * 4]);

    float m = -1e30f;
    #pragma unroll
    for (int kk = 0; kk < 4; ++kk)
        m = fmaxf(m, fmaxf(fmaxf(v4[kk][0], v4[kk][1]), fmaxf(v4[kk][2], v4[kk][3])));
    #pragma unroll
    for (int off = 1; off < 64; off <<= 1) m = fmaxf(m, __shfl_xor(m, off));

    float e[16];
    float ssum = 0.f;
    #pragma unroll
    for (int kk = 0; kk < 4; ++kk)
        #pragma unroll
        for (int ee = 0; ee < 4; ++ee) {
            const float t2 = __expf(v4[kk][ee] - m);
            e[kk * 4 + ee] = t2;
            ssum += t2;
        }
    #pragma unroll
    for (int off = 1; off < 64; off <<= 1) ssum += __shfl_xor(ssum, off);
    const float inv = 1.0f / ssum;

    {
        short4_t pv;
        #pragma unroll
        for (int ee = 0; ee < 4; ++ee) pv[ee] = (short)bf16_of(e[w * 4 + ee] * inv);
        *reinterpret_cast<short4_t*>(&P[i * BB + w * 256 + lane * 4]) = pv;
    }
}

// ---------------- K3a: partial out GEMM, split-K z=4 -----------------------------
__global__ __launch_bounds__(256) void out_partial(const unsigned short* __restrict__ P,
                                                   const unsigned short* __restrict__ xbfT,
                                                   float* __restrict__ part) {
    const int tid = threadIdx.x;
    const int wave = tid >> 6, lane = tid & 63;
    const int lcol = lane & 15;
    const int lk8  = (lane >> 4) * 8;
    const int i0 = blockIdx.y * 64 + wave * 16;
    const int d0 = blockIdx.x * 64;
    const int k0 = blockIdx.z * 256;

    f32x4 acc[4];
    #pragma unroll
    for (int nt = 0; nt < 4; ++nt) acc[nt] = (f32x4)0.0f;

    #pragma unroll
    for (int ks = 0; ks < 8; ++ks) {
        const short8_t a = *reinterpret_cast<const short8_t*>(
            &P[(i0 + lcol) * BB + k0 + ks * 32 + lk8]);
        #pragma unroll
        for (int nt = 0; nt < 4; ++nt) {
            const short8_t b = *reinterpret_cast<const short8_t*>(
                &xbfT[(d0 + nt * 16 + lcol) * BB + k0 + ks * 32 + lk8]);
            acc[nt] = __builtin_amdgcn_mfma_f32_16x16x32_bf16(a, b, acc[nt], 0, 0, 0);
        }
    }

    const int rbase = (lane >> 4) * 4;
    float* pz = part + (size_t)blockIdx.z * BB * DD;
    #pragma unroll
    for (int r = 0; r < 4; ++r)
        #pragma unroll
        for (int nt = 0; nt < 4; ++nt)
            pz[(i0 + rbase + r) * DD + d0 + nt * 16 + lcol] = acc[nt][r];
}

// ---------------- K3b: out = sum_z part[z] (P already normalized) ---------------
__global__ __launch_bounds__(256) void out_reduce(const float* __restrict__ part,
                                                  float* __restrict__ out) {
    const int idx = blockIdx.x * DD + threadIdx.x;
    out[idx] = (part[idx] + part[BB * DD + idx]) +
               (part[2 * BB * DD + idx] + part[3 * BB * DD + idx]);
}

// ---------------- launch ---------------------------------------------------------
extern "C" void kernel_launch(void* const* d_in, const int* in_sizes, int n_in,
                              void* d_out, int out_size, void* d_ws, size_t ws_size,
                              hipStream_t stream) {
    (void)in_sizes; (void)n_in; (void)out_size; (void)ws_size;
    const float* x = (const float*)d_in[0];
    // d_in[1] = x_mask (unused), d_in[3] = f (unused)
    const int* q = (const int*)d_in[2];
    const float* R = (const float*)d_in[4];
    float* out = (float*)d_out;

    char* ws = (char*)d_ws;
    unsigned short* xh8  = (unsigned short*)(ws);                  // 512 KB
    unsigned short* xbfT = (unsigned short*)(ws + (512u << 10));   // 512 KB
    unsigned short* P    = (unsigned short*)(ws + (1024u << 10));  // 2 MB
    float*          part = (float*)(ws + (3072u << 10));           // 4 MB (z=4)

    cvt_kernel<<<dim3(16, 4), 256, 0, stream>>>(x, xh8, xbfT);
    attn_kernel<<<dim3(BB), 256, 0, stream>>>(x, q, R, xh8, P);
    out_partial<<<dim3(4, 16, 4), 256, 0, stream>>>(P, xbfT, part);
    out_reduce<<<dim3(BB), 256, 0, stream>>>(part, out);
}